// Round 1
// baseline (1988.498 us; speedup 1.0000x reference)
//
#include <hip/hip_runtime.h>

typedef __bf16 bf16x8 __attribute__((ext_vector_type(8)));
typedef float  f32x4  __attribute__((ext_vector_type(4)));

union BF8 { unsigned short s[8]; bf16x8 v; };

__device__ __forceinline__ unsigned short f2bf(float x){
  unsigned u = __float_as_uint(x);
  u += 0x7fffu + ((u >> 16) & 1u);      // round-to-nearest-even
  return (unsigned short)(u >> 16);
}
__device__ __forceinline__ float sigm(float x){ return 1.0f/(1.0f + __expf(-x)); }
__device__ __forceinline__ float tanh_fast(float x){ return 1.0f - 2.0f/(__expf(2.0f*x)+1.0f); }

__device__ __forceinline__ unsigned encf(float f){
  unsigned u = __float_as_uint(f);
  return (u & 0x80000000u) ? ~u : (u | 0x80000000u);
}
__device__ __forceinline__ float decf(unsigned u){
  return (u & 0x80000000u) ? __uint_as_float(u ^ 0x80000000u) : __uint_as_float(~u);
}

__device__ __forceinline__ bf16x8 loadB(const unsigned short* __restrict__ W, int row, int koff){
  return *reinterpret_cast<const bf16x8*>(W + row*128 + koff);
}

// ---------------- prep: W -> bf16, lin_w -> transposed ----------------
__global__ void k_prep(const float* __restrict__ Wihf, const float* __restrict__ Whhf,
                       const float* __restrict__ linw,
                       unsigned short* __restrict__ Wih, unsigned short* __restrict__ Whh,
                       float* __restrict__ linT)
{
  int tid = blockIdx.x*256 + threadIdx.x;
  if (tid < 49152)        Wih[tid] = f2bf(Wihf[tid]);
  else if (tid < 98304)   Whh[tid-49152] = f2bf(Whhf[tid-49152]);
  else if (tid < 114688){ int i = tid - 98304; int k = i>>7, c = i&127; linT[i] = linw[c*128 + k]; }
}

// ---------------- edge index dtype sniff + normalize ----------------
__global__ void k_detect(const int* __restrict__ ei, unsigned* __restrict__ flag){
  int v = ei[2*threadIdx.x + 1];
  unsigned long long b = __ballot(v == 0);
  if (threadIdx.x == 0) flag[0] = (b == ~0ULL) ? 1u : 0u;   // all-high-words-zero => int64
}
__global__ void k_norm(const void* __restrict__ ei, const unsigned* __restrict__ flag,
                       int* __restrict__ src, int* __restrict__ dst, int E){
  int e = blockIdx.x*256 + threadIdx.x;
  if (e >= E) return;
  if (flag[0]){
    const long long* p = (const long long*)ei;
    src[e] = (int)p[e]; dst[e] = (int)p[(size_t)E + e];
  } else {
    const int* p = (const int*)ei;
    src[e] = p[e]; dst[e] = p[E + e];
  }
}

// ---------------- init: m=-inf, denom=0, out2=bias ----------------
__global__ void k_init(unsigned* __restrict__ m_enc, float* __restrict__ denom,
                       float* __restrict__ out2, const float* __restrict__ bias, int N){
  int tid = blockIdx.x*256 + threadIdx.x;
  if (tid < N*128) out2[tid] = bias[tid & 127];
  if (tid < N){ m_enc[tid] = 0x007FFFFFu; denom[tid] = 0.0f; }
}

// ---------------- GRU: one wave owns 16 nodes, all 16 steps ----------------
__global__ __launch_bounds__(256) void k_gru(
    const float* __restrict__ seq, const unsigned short* __restrict__ Wih,
    const unsigned short* __restrict__ Whh, const float* __restrict__ bih,
    const float* __restrict__ bhh, float* __restrict__ hout, int nWaves, int N)
{
  __shared__ unsigned short hbuf[4][16*128];
  const int lane = threadIdx.x & 63;
  const int wloc = threadIdx.x >> 6;
  const int wave = blockIdx.x*4 + wloc;
  if (wave >= nWaves) return;
  const int n0   = wave * 16;
  const int col4 = lane & 15;      // A-row / D-col within tile
  const int grp  = lane >> 4;      // k-chunk / D-row-group selector
  unsigned short* myh = hbuf[wloc];

  float br[8], bz[8], bin[8], bhn[8];
  #pragma unroll
  for (int ct=0; ct<8; ++ct){
    int c = ct*16 + col4;
    br [ct] = bih[c]       + bhh[c];
    bz [ct] = bih[128 + c] + bhh[128 + c];
    bin[ct] = bih[256 + c];
    bhn[ct] = bhh[256 + c];
  }
  f32x4 h[8];
  #pragma unroll
  for (int ct=0; ct<8; ++ct) h[ct] = (f32x4)0.0f;

  int nrow = n0 + col4; if (nrow >= N) nrow = N - 1;

  for (int t=0; t<16; ++t){
    bf16x8 xa[4], ha[4];
    const float* xr = seq + ((size_t)nrow*16 + t)*128 + grp*8;
    #pragma unroll
    for (int kt=0; kt<4; ++kt){
      f32x4 lo = *reinterpret_cast<const f32x4*>(xr + kt*32);
      f32x4 hi = *reinterpret_cast<const f32x4*>(xr + kt*32 + 4);
      BF8 u;
      #pragma unroll
      for (int j=0;j<4;++j){ u.s[j] = f2bf(lo[j]); u.s[4+j] = f2bf(hi[j]); }
      xa[kt] = u.v;
    }
    if (t == 0){
      BF8 uz;
      #pragma unroll
      for (int j=0;j<8;++j) uz.s[j] = 0;
      #pragma unroll
      for (int kt=0;kt<4;++kt) ha[kt] = uz.v;
    } else {
      #pragma unroll
      for (int kt=0;kt<4;++kt){
        int chunk = (kt*4 + grp) ^ (col4 & 7);
        ha[kt] = *reinterpret_cast<const bf16x8*>(myh + col4*128 + chunk*8);
      }
    }

    #pragma unroll
    for (int half=0; half<2; ++half){
      f32x4 ar[4], az[4], ain[4], ahn[4];
      #pragma unroll
      for (int j=0;j<4;++j){
        int ct = half*4 + j;
        ar [j] = (f32x4){br[ct],  br[ct],  br[ct],  br[ct]};
        az [j] = (f32x4){bz[ct],  bz[ct],  bz[ct],  bz[ct]};
        ain[j] = (f32x4){bin[ct], bin[ct], bin[ct], bin[ct]};
        ahn[j] = (f32x4){bhn[ct], bhn[ct], bhn[ct], bhn[ct]};
      }
      #pragma unroll
      for (int kt=0; kt<4; ++kt){
        int ko = kt*32 + grp*8;
        #pragma unroll
        for (int j=0;j<4;++j){
          int ct = half*4 + j;
          ar [j] = __builtin_amdgcn_mfma_f32_16x16x32_bf16(xa[kt], loadB(Wih,       ct*16 + col4, ko), ar [j], 0,0,0);
          ar [j] = __builtin_amdgcn_mfma_f32_16x16x32_bf16(ha[kt], loadB(Whh,       ct*16 + col4, ko), ar [j], 0,0,0);
          az [j] = __builtin_amdgcn_mfma_f32_16x16x32_bf16(xa[kt], loadB(Wih, 128 + ct*16 + col4, ko), az [j], 0,0,0);
          az [j] = __builtin_amdgcn_mfma_f32_16x16x32_bf16(ha[kt], loadB(Whh, 128 + ct*16 + col4, ko), az [j], 0,0,0);
          ain[j] = __builtin_amdgcn_mfma_f32_16x16x32_bf16(xa[kt], loadB(Wih, 256 + ct*16 + col4, ko), ain[j], 0,0,0);
          ahn[j] = __builtin_amdgcn_mfma_f32_16x16x32_bf16(ha[kt], loadB(Whh, 256 + ct*16 + col4, ko), ahn[j], 0,0,0);
        }
      }
      #pragma unroll
      for (int j=0;j<4;++j){
        int ct = half*4 + j;
        #pragma unroll
        for (int q=0;q<4;++q){
          float r  = sigm(ar[j][q]);
          float z  = sigm(az[j][q]);
          float nn = tanh_fast(ain[j][q] + r*ahn[j][q]);
          float hv = h[ct][q];
          hv = nn + z*(hv - nn);
          h[ct][q] = hv;
          int m = grp*4 + q;
          int c = ct*16 + col4;
          int chunk = (c >> 3) ^ (m & 7);
          myh[m*128 + chunk*8 + (c & 7)] = f2bf(hv);
        }
      }
    }
  }
  #pragma unroll
  for (int ct=0; ct<8; ++ct)
    #pragma unroll
    for (int q=0; q<4; ++q){
      int n = n0 + grp*4 + q;
      if (n < N) hout[(size_t)n*128 + ct*16 + col4] = h[ct][q];
    }
}

// ---------------- GAT linear: x = h @ lin_w^T (linT is pre-transposed) ----------------
__global__ __launch_bounds__(256) void k_gat1(
    const float* __restrict__ h, const float* __restrict__ linT,
    float* __restrict__ x, int N)
{
  __shared__ float hrows[16][128];
  const int half = threadIdx.x >> 7;
  const int c    = threadIdx.x & 127;
  const int nb   = blockIdx.x*16 + half*8;
  #pragma unroll
  for (int j=0;j<8;++j){
    int n = nb + j;
    hrows[half*8 + j][c] = (n < N) ? h[(size_t)n*128 + c] : 0.0f;
  }
  __syncthreads();
  float acc[8];
  #pragma unroll
  for (int j=0;j<8;++j) acc[j] = 0.f;
  #pragma unroll 4
  for (int k=0;k<128;++k){
    float w = linT[k*128 + c];
    #pragma unroll
    for (int j=0;j<8;++j) acc[j] += hrows[half*8 + j][k] * w;
  }
  #pragma unroll
  for (int j=0;j<8;++j){
    int n = nb + j;
    if (n < N) x[(size_t)n*128 + c] = acc[j];
  }
}

// ---------------- per-node attention scalars ----------------
__global__ __launch_bounds__(256) void k_att(const float* __restrict__ x,
    const float* __restrict__ att_s, const float* __restrict__ att_d,
    float* __restrict__ a_s, float* __restrict__ a_d, int N)
{
  int node = blockIdx.x*4 + (threadIdx.x >> 6);
  int lane = threadIdx.x & 63;
  if (node >= N) return;
  const float* xr = x + (size_t)node*128;
  float s = xr[lane]*att_s[lane] + xr[64+lane]*att_s[64+lane];
  float d = xr[lane]*att_d[lane] + xr[64+lane]*att_d[64+lane];
  #pragma unroll
  for (int off=32; off; off >>= 1){
    s += __shfl_down(s, off);
    d += __shfl_down(d, off);
  }
  if (lane == 0){ a_s[node] = s; a_d[node] = d; }
}

// ---------------- segment max ----------------
__global__ void k_emax(const int* __restrict__ src, const int* __restrict__ dst,
    const float* __restrict__ a_s, const float* __restrict__ a_d,
    unsigned* __restrict__ m_enc, int E, int EN)
{
  int e = blockIdx.x*256 + threadIdx.x;
  if (e >= EN) return;
  int s, d;
  if (e < E){ s = src[e]; d = dst[e]; } else { s = d = e - E; }
  float a = a_s[s] + a_d[d];
  a = a > 0.f ? a : 0.2f*a;
  atomicMax(&m_enc[d], encf(a));
}

// ---------------- segment sum of exp ----------------
__global__ void k_eden(const int* __restrict__ src, const int* __restrict__ dst,
    const float* __restrict__ a_s, const float* __restrict__ a_d,
    const unsigned* __restrict__ m_enc, float* __restrict__ denom, int E, int EN)
{
  int e = blockIdx.x*256 + threadIdx.x;
  if (e >= EN) return;
  int s, d;
  if (e < E){ s = src[e]; d = dst[e]; } else { s = d = e - E; }
  float a = a_s[s] + a_d[d];
  a = a > 0.f ? a : 0.2f*a;
  atomicAdd(&denom[d], __expf(a - decf(m_enc[d])));
}

// ---------------- weighted aggregation ----------------
__global__ __launch_bounds__(256) void k_agg(const int* __restrict__ src, const int* __restrict__ dst,
    const float* __restrict__ a_s, const float* __restrict__ a_d,
    const unsigned* __restrict__ m_enc, const float* __restrict__ denom,
    const float* __restrict__ x, float* __restrict__ out2, int E, int EN)
{
  __shared__ float cf[8];
  __shared__ int   ss[8], dd[8];
  const int tid = threadIdx.x;
  const long long ebase = (long long)blockIdx.x * 8;
  if (tid < 8){
    long long e = ebase + tid;
    if (e < EN){
      int s, d;
      if (e < E){ s = src[e]; d = dst[e]; } else { s = d = (int)(e - E); }
      float a = a_s[s] + a_d[d];
      a = a > 0.f ? a : 0.2f*a;
      float ex = __expf(a - decf(m_enc[d]));
      cf[tid] = ex / denom[d];
      ss[tid] = s; dd[tid] = d;
    } else { cf[tid] = 0.f; ss[tid] = 0; dd[tid] = 0; }
  }
  __syncthreads();
  const int half = tid >> 7, c = tid & 127;
  #pragma unroll
  for (int j=0;j<4;++j){
    int idx = half*4 + j;
    long long e = ebase + idx;
    if (e < EN){
      atomicAdd(&out2[(size_t)dd[idx]*128 + c], cf[idx] * x[(size_t)ss[idx]*128 + c]);
    }
  }
}

extern "C" void kernel_launch(void* const* d_in, const int* in_sizes, int n_in,
                              void* d_out, int out_size, void* d_ws, size_t ws_size,
                              hipStream_t stream)
{
  const float* seq  = (const float*)d_in[0];
  const void*  ei   = d_in[1];
  const float* Wihf = (const float*)d_in[2];
  const float* Whhf = (const float*)d_in[3];
  const float* bih  = (const float*)d_in[4];
  const float* bhh  = (const float*)d_in[5];
  const float* linw = (const float*)d_in[6];
  const float* atts = (const float*)d_in[7];
  const float* attd = (const float*)d_in[8];
  const float* gbias= (const float*)d_in[9];

  const int N  = in_sizes[0] / (16*128);
  const int E  = in_sizes[1] / 2;
  const int EN = E + N;

  char* ws = (char*)d_ws;
  unsigned short* Wih = (unsigned short*)(ws);
  unsigned short* Whh = (unsigned short*)(ws + 98304);
  float* linT = (float*)(ws + 196608);
  float* x    = (float*)(ws + 262144);
  size_t xend = 262144 + (size_t)N*128*4;
  float*    a_s   = (float*)   (ws + xend);
  float*    a_d   = (float*)   (ws + xend + (size_t)N*4);
  unsigned* m_enc = (unsigned*)(ws + xend + (size_t)N*8);
  float*    denom = (float*)   (ws + xend + (size_t)N*12);
  unsigned* flag  = (unsigned*)(ws + xend + (size_t)N*16);
  int*      srcA  = (int*)     (ws + xend + (size_t)N*16 + 64);
  int*      dstA  = srcA + E;

  float* hout = (float*)d_out;
  float* out2 = hout + (size_t)N*128;

  k_prep  <<<448, 256, 0, stream>>>(Wihf, Whhf, linw, Wih, Whh, linT);
  k_detect<<<1, 64, 0, stream>>>((const int*)ei, flag);
  k_norm  <<<(E + 255)/256, 256, 0, stream>>>(ei, flag, srcA, dstA, E);
  k_init  <<<(N*128 + 255)/256, 256, 0, stream>>>(m_enc, denom, out2, gbias, N);

  int nWaves = (N + 15)/16;
  k_gru   <<<(nWaves + 3)/4, 256, 0, stream>>>(seq, Wih, Whh, bih, bhh, hout, nWaves, N);

  k_gat1  <<<(N + 15)/16, 256, 0, stream>>>(hout, linT, x, N);
  k_att   <<<(N + 3)/4, 256, 0, stream>>>(x, atts, attd, a_s, a_d, N);
  k_emax  <<<(EN + 255)/256, 256, 0, stream>>>(srcA, dstA, a_s, a_d, m_enc, E, EN);
  k_eden  <<<(EN + 255)/256, 256, 0, stream>>>(srcA, dstA, a_s, a_d, m_enc, denom, E, EN);
  k_agg   <<<(EN + 7)/8, 256, 0, stream>>>(srcA, dstA, a_s, a_d, m_enc, denom, x, out2, E, EN);
}

// Round 2
// 1335.586 us; speedup vs baseline: 1.4889x; 1.4889x over previous
//
#include <hip/hip_runtime.h>

typedef __bf16 bf16x8 __attribute__((ext_vector_type(8)));
typedef float  f32x4  __attribute__((ext_vector_type(4)));
union BF8 { unsigned short s[8]; bf16x8 v; };

#define TCH 4   // timesteps per chunk (T=16 -> 4 chunks)

__device__ __forceinline__ unsigned short f2bf(float x){
  unsigned u = __float_as_uint(x);
  u += 0x7fffu + ((u >> 16) & 1u);      // round-to-nearest-even
  return (unsigned short)(u >> 16);
}
__device__ __forceinline__ float bf2f(unsigned short s){ return __uint_as_float(((unsigned)s) << 16); }
__device__ __forceinline__ float sigm(float x){ return 1.0f/(1.0f + __expf(-x)); }
__device__ __forceinline__ float tanh_fast(float x){ return 1.0f - 2.0f/(__expf(2.0f*x)+1.0f); }

// ---------------- prep: W -> bf16 pre-swizzled (chunk-of-8 ^ (row&7)) ----------------
__global__ void k_prep(const float* __restrict__ Wihf, const float* __restrict__ Whhf,
                       const float* __restrict__ linw,
                       unsigned short* __restrict__ Wih_sw, unsigned short* __restrict__ Whh_sw,
                       unsigned short* __restrict__ lin_sw)
{
  int tid = blockIdx.x*256 + threadIdx.x;
  if (tid < 49152){
    int row = tid >> 7, col = tid & 127;
    Wih_sw[row*128 + (((col>>3) ^ (row&7))<<3) + (col&7)] = f2bf(Wihf[tid]);
  } else if (tid < 98304){
    int i = tid - 49152; int row = i >> 7, col = i & 127;
    Whh_sw[row*128 + (((col>>3) ^ (row&7))<<3) + (col&7)] = f2bf(Whhf[i]);
  } else if (tid < 114688){
    int i = tid - 98304; int row = i >> 7, col = i & 127;
    lin_sw[row*128 + (((col>>3) ^ (row&7))<<3) + (col&7)] = f2bf(linw[i]);
  }
}

// ---------------- edge index dtype sniff + normalize ----------------
__global__ void k_detect(const int* __restrict__ ei, unsigned* __restrict__ flag){
  int v = ei[2*threadIdx.x + 1];
  unsigned long long b = __ballot(v == 0);
  if (threadIdx.x == 0) flag[0] = (b == ~0ULL) ? 1u : 0u;
}
__global__ void k_norm(const void* __restrict__ ei, const unsigned* __restrict__ flag,
                       int* __restrict__ src, int* __restrict__ dst, int E){
  int e = blockIdx.x*256 + threadIdx.x;
  if (e >= E) return;
  if (flag[0]){
    const long long* p = (const long long*)ei;
    src[e] = (int)p[e]; dst[e] = (int)p[(size_t)E + e];
  } else {
    const int* p = (const int*)ei;
    src[e] = p[e]; dst[e] = p[E + e];
  }
}

// ---------------- init: denom=0, out2=bias ----------------
__global__ void k_init(float* __restrict__ denom, float* __restrict__ out2,
                       const float* __restrict__ bias, int N){
  int tid = blockIdx.x*256 + threadIdx.x;
  if (tid < N*128) out2[tid] = bias[tid & 127];
  if (tid < N) denom[tid] = 0.0f;
}

// ---------------- phase A: gi = x @ W_ih^T + biases, bf16, per-lane layout ----------------
__global__ __launch_bounds__(512) void k_phA(
    const float* __restrict__ seq, const unsigned short* __restrict__ Wih_sw,
    const float* __restrict__ bih, const float* __restrict__ bhh,
    unsigned short* __restrict__ gi, int nT, int N, int chunk)
{
  __shared__ unsigned short Wlds[49152];
  const int tid = threadIdx.x;
  for (int i = tid; i < 6144; i += 512)
    ((uint4*)Wlds)[i] = ((const uint4*)Wih_sw)[i];
  __syncthreads();
  const int lane = tid & 63, wloc = tid >> 6;
  const int col4 = lane & 15, grp = lane >> 4;

  float bias[24];
  #pragma unroll
  for (int g=0; g<24; ++g){
    int ch = g*16 + col4;
    bias[g] = bih[ch] + (g < 16 ? bhh[ch] : 0.0f);   // fold b_hh into r,z; NOT n
  }

  const int nJobs = nT * TCH;
  for (int job = blockIdx.x*8 + wloc; job < nJobs; job += 256*8){
    const int tile = job % nT;
    const int tloc = job / nT;
    const int t = chunk*TCH + tloc;
    int nrow = tile*16 + col4; if (nrow >= N) nrow = N-1;
    const float* xr = seq + ((size_t)nrow*16 + t)*128 + grp*8;
    bf16x8 xa[4];
    #pragma unroll
    for (int kt=0; kt<4; ++kt){
      f32x4 lo = *(const f32x4*)(xr + kt*32);
      f32x4 hi = *(const f32x4*)(xr + kt*32 + 4);
      BF8 u;
      #pragma unroll
      for (int j=0;j<4;++j){ u.s[j]=f2bf(lo[j]); u.s[4+j]=f2bf(hi[j]); }
      xa[kt] = u.v;
    }
    f32x4 acc[24];
    #pragma unroll
    for (int g=0; g<24; ++g) acc[g] = (f32x4){bias[g],bias[g],bias[g],bias[g]};
    #pragma unroll
    for (int kt=0; kt<4; ++kt){
      #pragma unroll
      for (int g=0; g<24; ++g){
        int row = g*16 + col4;
        const bf16x8 b = *(const bf16x8*)(Wlds + row*128 + (((kt*4+grp) ^ (row&7))<<3));
        acc[g] = __builtin_amdgcn_mfma_f32_16x16x32_bf16(xa[kt], b, acc[g], 0,0,0);
      }
    }
    // store 96 bf16/lane, [j][lane] interleave => coalesced 1KB per instruction
    bf16x8* dst = (bf16x8*)gi + ((size_t)(tloc*nT + tile)*12)*64;
    #pragma unroll
    for (int j=0; j<12; ++j){
      BF8 u;
      #pragma unroll
      for (int e=0; e<8; ++e){
        int idx = j*8+e;
        u.s[e] = f2bf(acc[idx>>2][idx&3]);
      }
      dst[(size_t)j*64 + lane] = u.v;
    }
  }
}

// ---------------- phase B: sequential GRU steps, W_hh in LDS, h in registers ----------------
__global__ __launch_bounds__(512) void k_phB(
    const unsigned short* __restrict__ Whh_sw, const float* __restrict__ bhh,
    const unsigned short* __restrict__ gi, float* __restrict__ hstate,
    float* __restrict__ hout, int nT, int N, int chunk, int last)
{
  __shared__ unsigned short Wlds[49152];
  __shared__ unsigned short hbuf[8][2048];
  const int tid = threadIdx.x;
  for (int i = tid; i < 6144; i += 512)
    ((uint4*)Wlds)[i] = ((const uint4*)Whh_sw)[i];
  __syncthreads();
  const int lane = tid & 63, wloc = tid >> 6;
  const int col4 = lane & 15, grp = lane >> 4;
  unsigned short* myh = hbuf[wloc];

  float bn[8];
  #pragma unroll
  for (int ct=0; ct<8; ++ct) bn[ct] = bhh[256 + ct*16 + col4];

  for (int tile = blockIdx.x + 256*wloc; tile < nT; tile += 2048){
    float h[8][4];
    if (chunk == 0){
      #pragma unroll
      for (int ct=0;ct<8;++ct)
        #pragma unroll
        for (int q=0;q<4;++q) h[ct][q] = 0.0f;
    } else {
      const float* hp = hstate + ((size_t)tile*64 + lane)*32;
      #pragma unroll
      for (int ct=0;ct<8;++ct)
        #pragma unroll
        for (int q=0;q<4;++q) h[ct][q] = hp[ct*4+q];
      #pragma unroll
      for (int ct=0;ct<8;++ct)
        #pragma unroll
        for (int q=0;q<4;++q){
          int m = grp*4 + q, c = ct*16 + col4;
          int c2 = (c>>3) ^ (m&7);
          myh[m*128 + c2*8 + (c&7)] = f2bf(h[ct][q]);
        }
    }
    for (int tloc = 0; tloc < TCH; ++tloc){
      const bf16x8* gp = (const bf16x8*)gi + ((size_t)(tloc*nT + tile)*12)*64;
      BF8 gfr[12];
      #pragma unroll
      for (int j=0;j<12;++j) gfr[j].v = gp[(size_t)j*64 + lane];

      bf16x8 ha[4];
      if (chunk == 0 && tloc == 0){
        BF8 uz;
        #pragma unroll
        for (int j=0;j<8;++j) uz.s[j]=0;
        #pragma unroll
        for (int kt=0;kt<4;++kt) ha[kt]=uz.v;
      } else {
        #pragma unroll
        for (int kt=0;kt<4;++kt){
          int ck = (kt*4+grp) ^ (col4&7);
          ha[kt] = *(const bf16x8*)(myh + col4*128 + ck*8);
        }
      }
      #pragma unroll
      for (int hf=0; hf<2; ++hf){
        f32x4 a_r[4], a_z[4], a_n[4];
        #pragma unroll
        for (int j=0;j<4;++j){
          a_r[j] = (f32x4)0.0f; a_z[j] = (f32x4)0.0f;
          float b = bn[hf*4+j];
          a_n[j] = (f32x4){b,b,b,b};
        }
        #pragma unroll
        for (int kt=0;kt<4;++kt){
          #pragma unroll
          for (int j=0;j<4;++j){
            int ct = hf*4+j;
            int rr = (     ct)*16 + col4;
            int rz = ( 8 + ct)*16 + col4;
            int rn = (16 + ct)*16 + col4;
            const bf16x8 br  = *(const bf16x8*)(Wlds + rr*128 + (((kt*4+grp)^(rr&7))<<3));
            const bf16x8 bz  = *(const bf16x8*)(Wlds + rz*128 + (((kt*4+grp)^(rz&7))<<3));
            const bf16x8 bnn = *(const bf16x8*)(Wlds + rn*128 + (((kt*4+grp)^(rn&7))<<3));
            a_r[j] = __builtin_amdgcn_mfma_f32_16x16x32_bf16(ha[kt], br,  a_r[j], 0,0,0);
            a_z[j] = __builtin_amdgcn_mfma_f32_16x16x32_bf16(ha[kt], bz,  a_z[j], 0,0,0);
            a_n[j] = __builtin_amdgcn_mfma_f32_16x16x32_bf16(ha[kt], bnn, a_n[j], 0,0,0);
          }
        }
        #pragma unroll
        for (int j=0;j<4;++j){
          int ct = hf*4+j;
          #pragma unroll
          for (int q=0;q<4;++q){
            int ir = (     ct)*4+q;
            int iz = ( 8 + ct)*4+q;
            int in = (16 + ct)*4+q;
            float gr = a_r[j][q] + bf2f(gfr[ir>>3].s[ir&7]);
            float gz = a_z[j][q] + bf2f(gfr[iz>>3].s[iz&7]);
            float gn = bf2f(gfr[in>>3].s[in&7]);
            float r = sigm(gr), z = sigm(gz);
            float nn = tanh_fast(gn + r * a_n[j][q]);
            float hv = h[ct][q];
            hv = nn + z*(hv - nn);
            h[ct][q] = hv;
            int m = grp*4 + q, c = ct*16 + col4;
            int c2 = (c>>3) ^ (m&7);
            myh[m*128 + c2*8 + (c&7)] = f2bf(hv);
          }
        }
      }
    }
    float* hp = hstate + ((size_t)tile*64 + lane)*32;
    #pragma unroll
    for (int ct=0;ct<8;++ct)
      #pragma unroll
      for (int q=0;q<4;++q) hp[ct*4+q] = h[ct][q];
    if (last){
      #pragma unroll
      for (int ct=0;ct<8;++ct)
        #pragma unroll
        for (int q=0;q<4;++q){
          int n = tile*16 + grp*4 + q;
          if (n < N) hout[(size_t)n*128 + ct*16 + col4] = h[ct][q];
        }
    }
  }
}

// ---------------- GAT linear (MFMA) + fused attention scalars ----------------
__global__ __launch_bounds__(256) void k_gat1(
    const float* __restrict__ hsrc, const unsigned short* __restrict__ lin_sw,
    const float* __restrict__ att_s, const float* __restrict__ att_d,
    float* __restrict__ x, float* __restrict__ a_s, float* __restrict__ a_d, int N, int nT)
{
  __shared__ unsigned short Llds[16384];
  const int tid = threadIdx.x;
  for (int i = tid; i < 2048; i += 256)
    ((uint4*)Llds)[i] = ((const uint4*)lin_sw)[i];
  __syncthreads();
  const int lane = tid & 63, wloc = tid >> 6;
  const int col4 = lane & 15, grp = lane >> 4;
  const int tile = blockIdx.x*4 + wloc;
  if (tile >= nT) return;
  float ats[8], atd[8];
  #pragma unroll
  for (int ct=0;ct<8;++ct){ ats[ct] = att_s[ct*16+col4]; atd[ct] = att_d[ct*16+col4]; }
  int nrow = tile*16 + col4; if (nrow >= N) nrow = N-1;
  const float* xr = hsrc + (size_t)nrow*128 + grp*8;
  bf16x8 xa[4];
  #pragma unroll
  for (int kt=0;kt<4;++kt){
    f32x4 lo = *(const f32x4*)(xr + kt*32);
    f32x4 hi = *(const f32x4*)(xr + kt*32 + 4);
    BF8 u;
    #pragma unroll
    for (int j=0;j<4;++j){ u.s[j]=f2bf(lo[j]); u.s[4+j]=f2bf(hi[j]); }
    xa[kt] = u.v;
  }
  f32x4 acc[8];
  #pragma unroll
  for (int ct=0;ct<8;++ct) acc[ct] = (f32x4)0.0f;
  #pragma unroll
  for (int kt=0;kt<4;++kt){
    #pragma unroll
    for (int ct=0;ct<8;++ct){
      int row = ct*16+col4;
      const bf16x8 b = *(const bf16x8*)(Llds + row*128 + (((kt*4+grp)^(row&7))<<3));
      acc[ct] = __builtin_amdgcn_mfma_f32_16x16x32_bf16(xa[kt], b, acc[ct], 0,0,0);
    }
  }
  float ss[4] = {0,0,0,0}, dd[4] = {0,0,0,0};
  #pragma unroll
  for (int ct=0;ct<8;++ct)
    #pragma unroll
    for (int q=0;q<4;++q){
      float xv = acc[ct][q];
      int n = tile*16 + grp*4 + q;
      if (n < N) x[(size_t)n*128 + ct*16 + col4] = xv;
      ss[q] += xv * ats[ct];
      dd[q] += xv * atd[ct];
    }
  #pragma unroll
  for (int m=1; m<16; m<<=1){
    #pragma unroll
    for (int q=0;q<4;++q){
      ss[q] += __shfl_xor(ss[q], m);
      dd[q] += __shfl_xor(dd[q], m);
    }
  }
  if (col4 == 0){
    #pragma unroll
    for (int q=0;q<4;++q){
      int n = tile*16 + grp*4 + q;
      if (n < N){ a_s[n] = ss[q]; a_d[n] = dd[q]; }
    }
  }
}

// ---------------- segment sum of exp (no max-sub: |alpha| small, identity for softmax) ---
__global__ void k_eden(const int* __restrict__ src, const int* __restrict__ dst,
    const float* __restrict__ a_s, const float* __restrict__ a_d,
    float* __restrict__ denom, float* __restrict__ ex, int E, int EN)
{
  int e = blockIdx.x*256 + threadIdx.x;
  if (e >= EN) return;
  int s, d;
  if (e < E){ s = src[e]; d = dst[e]; } else { s = d = e - E; }
  float a = a_s[s] + a_d[d];
  a = a > 0.f ? a : 0.2f*a;
  float v = __expf(a);
  ex[e] = v;
  atomicAdd(&denom[d], v);
}

// ---------------- weighted aggregation ----------------
__global__ __launch_bounds__(256) void k_agg(const int* __restrict__ src, const int* __restrict__ dst,
    const float* __restrict__ ex, const float* __restrict__ denom,
    const float* __restrict__ x, float* __restrict__ out2, int E, int EN)
{
  __shared__ float cf[8];
  __shared__ int   ss[8], dd2[8];
  const int tid = threadIdx.x;
  const long long ebase = (long long)blockIdx.x * 8;
  if (tid < 8){
    long long e = ebase + tid;
    if (e < EN){
      int s, d;
      if (e < E){ s = src[e]; d = dst[e]; } else { s = d = (int)(e - E); }
      cf[tid] = ex[e] / denom[d];
      ss[tid] = s; dd2[tid] = d;
    } else { cf[tid] = 0.f; ss[tid] = 0; dd2[tid] = 0; }
  }
  __syncthreads();
  const int half = tid >> 7, c = tid & 127;
  #pragma unroll
  for (int j=0;j<4;++j){
    int idx = half*4 + j;
    long long e = ebase + idx;
    if (e < EN){
      atomicAdd(&out2[(size_t)dd2[idx]*128 + c], cf[idx] * x[(size_t)ss[idx]*128 + c]);
    }
  }
}

extern "C" void kernel_launch(void* const* d_in, const int* in_sizes, int n_in,
                              void* d_out, int out_size, void* d_ws, size_t ws_size,
                              hipStream_t stream)
{
  const float* seq  = (const float*)d_in[0];
  const void*  ei   = d_in[1];
  const float* Wihf = (const float*)d_in[2];
  const float* Whhf = (const float*)d_in[3];
  const float* bih  = (const float*)d_in[4];
  const float* bhh  = (const float*)d_in[5];
  const float* linw = (const float*)d_in[6];
  const float* atts = (const float*)d_in[7];
  const float* attd = (const float*)d_in[8];
  const float* gbias= (const float*)d_in[9];

  const int N  = in_sizes[0] / (16*128);
  const int E  = in_sizes[1] / 2;
  const int EN = E + N;
  const int nT = (N + 15) / 16;

  char* ws = (char*)d_ws;
  size_t off = 0;
  auto alloc = [&](size_t bytes) -> char* {
    char* p = ws + off;
    off = (off + bytes + 255) & ~(size_t)255;
    return p;
  };
  unsigned short* Wih_sw = (unsigned short*)alloc(98304);
  unsigned short* Whh_sw = (unsigned short*)alloc(98304);
  unsigned short* lin_sw = (unsigned short*)alloc(32768);
  float*    x      = (float*)   alloc((size_t)N*128*4);
  float*    a_s    = (float*)   alloc((size_t)N*4);
  float*    a_d    = (float*)   alloc((size_t)N*4);
  float*    denom  = (float*)   alloc((size_t)N*4);
  float*    hstate = (float*)   alloc((size_t)N*128*4);
  unsigned* flag   = (unsigned*)alloc(64);
  int*      srcA   = (int*)     alloc((size_t)E*4);
  int*      dstA   = (int*)     alloc((size_t)E*4);
  float*    exbuf  = (float*)   alloc((size_t)EN*4);
  unsigned short* gi = (unsigned short*)alloc((size_t)TCH*nT*64*96*2);

  float* hout = (float*)d_out;
  float* out2 = hout + (size_t)N*128;

  k_prep  <<<448, 256, 0, stream>>>(Wihf, Whhf, linw, Wih_sw, Whh_sw, lin_sw);
  k_detect<<<1, 64, 0, stream>>>((const int*)ei, flag);
  k_norm  <<<(E + 255)/256, 256, 0, stream>>>(ei, flag, srcA, dstA, E);
  k_init  <<<(N*128 + 255)/256, 256, 0, stream>>>(denom, out2, gbias, N);

  for (int c = 0; c < 16/TCH; ++c){
    k_phA<<<256, 512, 0, stream>>>(seq, Wih_sw, bih, bhh, gi, nT, N, c);
    k_phB<<<256, 512, 0, stream>>>(Whh_sw, bhh, gi, hstate, hout, nT, N, c, c == (16/TCH - 1));
  }

  k_gat1<<<(nT + 3)/4, 256, 0, stream>>>(hout, lin_sw, atts, attd, x, a_s, a_d, N, nT);
  k_eden<<<(EN + 255)/256, 256, 0, stream>>>(srcA, dstA, a_s, a_d, denom, exbuf, E, EN);
  k_agg <<<(EN + 7)/8, 256, 0, stream>>>(srcA, dstA, exbuf, denom, x, out2, E, EN);
}

// Round 3
// 1219.081 us; speedup vs baseline: 1.6311x; 1.0956x over previous
//
#include <hip/hip_runtime.h>

typedef __bf16 bf16x8 __attribute__((ext_vector_type(8)));
typedef float  f32x4  __attribute__((ext_vector_type(4)));
union BF8 { unsigned short s[8]; bf16x8 v; };

__device__ __forceinline__ unsigned short f2bf(float x){
  unsigned u = __float_as_uint(x);
  u += 0x7fffu + ((u >> 16) & 1u);      // round-to-nearest-even
  return (unsigned short)(u >> 16);
}
__device__ __forceinline__ float bf2f(unsigned short s){ return __uint_as_float(((unsigned)s) << 16); }
__device__ __forceinline__ float sigm(float x){ return 1.0f/(1.0f + __expf(-x)); }
__device__ __forceinline__ float tanh_fast(float x){ return 1.0f - 2.0f/(__expf(2.0f*x)+1.0f); }

// ---------------- prep: W -> bf16 pre-swizzled (chunk-of-8 ^ (row&7)) ----------------
__global__ void k_prep(const float* __restrict__ Wihf, const float* __restrict__ Whhf,
                       const float* __restrict__ linw,
                       unsigned short* __restrict__ Wih_sw, unsigned short* __restrict__ Whh_sw,
                       unsigned short* __restrict__ lin_sw)
{
  int tid = blockIdx.x*256 + threadIdx.x;
  if (tid < 49152){
    int row = tid >> 7, col = tid & 127;
    Wih_sw[row*128 + (((col>>3) ^ (row&7))<<3) + (col&7)] = f2bf(Wihf[tid]);
  } else if (tid < 98304){
    int i = tid - 49152; int row = i >> 7, col = i & 127;
    Whh_sw[row*128 + (((col>>3) ^ (row&7))<<3) + (col&7)] = f2bf(Whhf[i]);
  } else if (tid < 114688){
    int i = tid - 98304; int row = i >> 7, col = i & 127;
    lin_sw[row*128 + (((col>>3) ^ (row&7))<<3) + (col&7)] = f2bf(linw[i]);
  }
}

// ---------------- edge index dtype sniff ----------------
__global__ void k_detect(const int* __restrict__ ei, unsigned* __restrict__ flag){
  int v = ei[2*threadIdx.x + 1];
  unsigned long long b = __ballot(v == 0);
  if (threadIdx.x == 0) flag[0] = (b == ~0ULL) ? 1u : 0u;
}

__global__ void k_zero(int* __restrict__ deg, int N){
  int tid = blockIdx.x*256 + threadIdx.x;
  if (tid < N) deg[tid] = 0;
}

// normalize edges + histogram destinations
__global__ void k_norm(const void* __restrict__ ei, const unsigned* __restrict__ flag,
                       int* __restrict__ src, int* __restrict__ dst, int* __restrict__ deg, int E){
  int e = blockIdx.x*256 + threadIdx.x;
  if (e >= E) return;
  int s, d;
  if (flag[0]){
    const long long* p = (const long long*)ei;
    s = (int)p[e]; d = (int)p[(size_t)E + e];
  } else {
    const int* p = (const int*)ei;
    s = p[e]; d = p[E + e];
  }
  src[e] = s; dst[e] = d;
  atomicAdd(&deg[d], 1);
}

// single-wave exclusive scan over deg -> off[0..N], zero cursors
__global__ void k_scan(const int* __restrict__ deg, int* __restrict__ off,
                       int* __restrict__ cur, int N){
  int lane = threadIdx.x;
  int carry = 0;
  for (int base = 0; base < N; base += 64){
    int i = base + lane;
    int v = (i < N) ? deg[i] : 0;
    int inc = v;
    #pragma unroll
    for (int d2 = 1; d2 < 64; d2 <<= 1){
      int u = __shfl_up(inc, d2);
      if (lane >= d2) inc += u;
    }
    if (i < N){ off[i] = carry + inc - v; cur[i] = 0; }
    carry += __shfl(inc, 63);
  }
  if (lane == 0) off[N] = carry;
}

// scatter edge sources into CSR
__global__ void k_scatter(const int* __restrict__ src, const int* __restrict__ dst,
                          const int* __restrict__ off, int* __restrict__ cur,
                          int* __restrict__ eid, int E){
  int e = blockIdx.x*256 + threadIdx.x;
  if (e >= E) return;
  int d = dst[e];
  int p = off[d] + atomicAdd(&cur[d], 1);
  eid[p] = src[e];
}

// ---------------- phase A: gi = x @ W_ih^T + biases, bf16, per-lane layout ----------------
__global__ __launch_bounds__(512) void k_phA(
    const float* __restrict__ seq, const unsigned short* __restrict__ Wih_sw,
    const float* __restrict__ bih, const float* __restrict__ bhh,
    unsigned short* __restrict__ gi, int nT, int N, int tch, int chunk)
{
  __shared__ unsigned short Wlds[49152];
  const int tid = threadIdx.x;
  for (int i = tid; i < 6144; i += 512)
    ((uint4*)Wlds)[i] = ((const uint4*)Wih_sw)[i];
  __syncthreads();
  const int lane = tid & 63, wloc = tid >> 6;
  const int col4 = lane & 15, grp = lane >> 4;

  float bias[24];
  #pragma unroll
  for (int g=0; g<24; ++g){
    int ch = g*16 + col4;
    bias[g] = bih[ch] + (g < 16 ? bhh[ch] : 0.0f);   // fold b_hh into r,z; NOT n
  }

  const int nJobs = nT * tch;
  for (int job = blockIdx.x*8 + wloc; job < nJobs; job += 2048){
    const int tile = job % nT;
    const int tloc = job / nT;
    const int t = chunk*tch + tloc;
    int nrow = tile*16 + col4; if (nrow >= N) nrow = N-1;
    const float* xr = seq + ((size_t)nrow*16 + t)*128 + grp*8;
    bf16x8 xa[4];
    #pragma unroll
    for (int kt=0; kt<4; ++kt){
      f32x4 lo = *(const f32x4*)(xr + kt*32);
      f32x4 hi = *(const f32x4*)(xr + kt*32 + 4);
      BF8 u;
      #pragma unroll
      for (int j=0;j<4;++j){ u.s[j]=f2bf(lo[j]); u.s[4+j]=f2bf(hi[j]); }
      xa[kt] = u.v;
    }
    f32x4 acc[24];
    #pragma unroll
    for (int g=0; g<24; ++g) acc[g] = (f32x4){bias[g],bias[g],bias[g],bias[g]};
    #pragma unroll
    for (int kt=0; kt<4; ++kt){
      #pragma unroll
      for (int g=0; g<24; ++g){
        int row = g*16 + col4;
        const bf16x8 b = *(const bf16x8*)(Wlds + row*128 + (((kt*4+grp) ^ (row&7))<<3));
        acc[g] = __builtin_amdgcn_mfma_f32_16x16x32_bf16(xa[kt], b, acc[g], 0,0,0);
      }
    }
    bf16x8* dst = (bf16x8*)gi + ((size_t)(tloc*nT + tile)*12)*64;
    #pragma unroll
    for (int j=0; j<12; ++j){
      BF8 u;
      #pragma unroll
      for (int e=0; e<8; ++e){
        int idx = j*8+e;
        u.s[e] = f2bf(acc[idx>>2][idx&3]);
      }
      dst[(size_t)j*64 + lane] = u.v;
    }
  }
}

// ---------------- phase B: sequential GRU steps, W_hh in LDS, h in registers ----------------
__global__ __launch_bounds__(512) void k_phB(
    const unsigned short* __restrict__ Whh_sw, const float* __restrict__ bhh,
    const unsigned short* __restrict__ gi, float* __restrict__ hstate,
    float* __restrict__ hout, int nT, int N, int tch, int chunk, int last)
{
  __shared__ unsigned short Wlds[49152];
  __shared__ unsigned short hbuf[8][2048];
  const int tid = threadIdx.x;
  for (int i = tid; i < 6144; i += 512)
    ((uint4*)Wlds)[i] = ((const uint4*)Whh_sw)[i];
  __syncthreads();
  const int lane = tid & 63, wloc = tid >> 6;
  const int col4 = lane & 15, grp = lane >> 4;
  unsigned short* myh = hbuf[wloc];

  float bn[8];
  #pragma unroll
  for (int ct=0; ct<8; ++ct) bn[ct] = bhh[256 + ct*16 + col4];

  for (int tile = blockIdx.x + 256*wloc; tile < nT; tile += 2048){
    float h[8][4];
    if (chunk == 0){
      #pragma unroll
      for (int ct=0;ct<8;++ct)
        #pragma unroll
        for (int q=0;q<4;++q) h[ct][q] = 0.0f;
    } else {
      const float* hp = hstate + ((size_t)tile*64 + lane)*32;
      #pragma unroll
      for (int ct=0;ct<8;++ct)
        #pragma unroll
        for (int q=0;q<4;++q) h[ct][q] = hp[ct*4+q];
      #pragma unroll
      for (int ct=0;ct<8;++ct)
        #pragma unroll
        for (int q=0;q<4;++q){
          int m = grp*4 + q, c = ct*16 + col4;
          int c2 = (c>>3) ^ (m&7);
          myh[m*128 + c2*8 + (c&7)] = f2bf(h[ct][q]);
        }
    }
    const bf16x8* gbase = (const bf16x8*)gi;
    BF8 gA[12], gB[12];
    {
      const bf16x8* gp = gbase + ((size_t)tile*12)*64;
      #pragma unroll
      for (int j=0;j<12;++j) gA[j].v = gp[(size_t)j*64 + lane];
    }

    auto gstep = [&](int tloc, BF8* gin, BF8* gpre){
      if (tloc + 1 < tch){
        const bf16x8* gp2 = gbase + ((size_t)((tloc+1)*nT + tile)*12)*64;
        #pragma unroll
        for (int j=0;j<12;++j) gpre[j].v = gp2[(size_t)j*64 + lane];
      }
      bf16x8 ha[4];
      if (chunk == 0 && tloc == 0){
        BF8 uz;
        #pragma unroll
        for (int j=0;j<8;++j) uz.s[j]=0;
        #pragma unroll
        for (int kt=0;kt<4;++kt) ha[kt]=uz.v;
      } else {
        #pragma unroll
        for (int kt=0;kt<4;++kt){
          int ck = (kt*4+grp) ^ (col4&7);
          ha[kt] = *(const bf16x8*)(myh + col4*128 + ck*8);
        }
      }
      #pragma unroll
      for (int hf=0; hf<2; ++hf){
        f32x4 a_r[4], a_z[4], a_n[4];
        #pragma unroll
        for (int j=0;j<4;++j){
          a_r[j] = (f32x4)0.0f; a_z[j] = (f32x4)0.0f;
          float b = bn[hf*4+j];
          a_n[j] = (f32x4){b,b,b,b};
        }
        #pragma unroll
        for (int kt=0;kt<4;++kt){
          #pragma unroll
          for (int j=0;j<4;++j){
            int ct = hf*4+j;
            int rr = (     ct)*16 + col4;
            int rz = ( 8 + ct)*16 + col4;
            int rn = (16 + ct)*16 + col4;
            const bf16x8 br  = *(const bf16x8*)(Wlds + rr*128 + (((kt*4+grp)^(rr&7))<<3));
            const bf16x8 bz  = *(const bf16x8*)(Wlds + rz*128 + (((kt*4+grp)^(rz&7))<<3));
            const bf16x8 bnn = *(const bf16x8*)(Wlds + rn*128 + (((kt*4+grp)^(rn&7))<<3));
            a_r[j] = __builtin_amdgcn_mfma_f32_16x16x32_bf16(ha[kt], br,  a_r[j], 0,0,0);
            a_z[j] = __builtin_amdgcn_mfma_f32_16x16x32_bf16(ha[kt], bz,  a_z[j], 0,0,0);
            a_n[j] = __builtin_amdgcn_mfma_f32_16x16x32_bf16(ha[kt], bnn, a_n[j], 0,0,0);
          }
        }
        #pragma unroll
        for (int j=0;j<4;++j){
          int ct = hf*4+j;
          #pragma unroll
          for (int q=0;q<4;++q){
            int ir = (     ct)*4+q;
            int iz = ( 8 + ct)*4+q;
            int in = (16 + ct)*4+q;
            float gr = a_r[j][q] + bf2f(gin[ir>>3].s[ir&7]);
            float gz = a_z[j][q] + bf2f(gin[iz>>3].s[iz&7]);
            float gn = bf2f(gin[in>>3].s[in&7]);
            float r = sigm(gr), z = sigm(gz);
            float nn = tanh_fast(gn + r * a_n[j][q]);
            float hv = h[ct][q];
            hv = nn + z*(hv - nn);
            h[ct][q] = hv;
            int m = grp*4 + q, c = ct*16 + col4;
            int c2 = (c>>3) ^ (m&7);
            myh[m*128 + c2*8 + (c&7)] = f2bf(hv);
          }
        }
      }
    };

    for (int tloc = 0; tloc < tch; tloc += 2){
      gstep(tloc, gA, gB);
      if (tloc + 1 < tch) gstep(tloc+1, gB, gA);
    }

    if (last){
      #pragma unroll
      for (int ct=0;ct<8;++ct)
        #pragma unroll
        for (int q=0;q<4;++q){
          int n = tile*16 + grp*4 + q;
          if (n < N) hout[(size_t)n*128 + ct*16 + col4] = h[ct][q];
        }
    } else {
      float* hp = hstate + ((size_t)tile*64 + lane)*32;
      #pragma unroll
      for (int ct=0;ct<8;++ct)
        #pragma unroll
        for (int q=0;q<4;++q) hp[ct*4+q] = h[ct][q];
    }
  }
}

// ---------------- GAT linear (MFMA) + fused attention scalars; x stored bf16 ----------------
__global__ __launch_bounds__(256) void k_gat1(
    const float* __restrict__ hsrc, const unsigned short* __restrict__ lin_sw,
    const float* __restrict__ att_s, const float* __restrict__ att_d,
    unsigned short* __restrict__ xbf, float* __restrict__ a_s, float* __restrict__ a_d,
    int N, int nT)
{
  __shared__ unsigned short Llds[16384];
  const int tid = threadIdx.x;
  for (int i = tid; i < 2048; i += 256)
    ((uint4*)Llds)[i] = ((const uint4*)lin_sw)[i];
  __syncthreads();
  const int lane = tid & 63, wloc = tid >> 6;
  const int col4 = lane & 15, grp = lane >> 4;
  const int tile = blockIdx.x*4 + wloc;
  if (tile >= nT) return;
  float ats[8], atd[8];
  #pragma unroll
  for (int ct=0;ct<8;++ct){ ats[ct] = att_s[ct*16+col4]; atd[ct] = att_d[ct*16+col4]; }
  int nrow = tile*16 + col4; if (nrow >= N) nrow = N-1;
  const float* xr = hsrc + (size_t)nrow*128 + grp*8;
  bf16x8 xa[4];
  #pragma unroll
  for (int kt=0;kt<4;++kt){
    f32x4 lo = *(const f32x4*)(xr + kt*32);
    f32x4 hi = *(const f32x4*)(xr + kt*32 + 4);
    BF8 u;
    #pragma unroll
    for (int j=0;j<4;++j){ u.s[j]=f2bf(lo[j]); u.s[4+j]=f2bf(hi[j]); }
    xa[kt] = u.v;
  }
  f32x4 acc[8];
  #pragma unroll
  for (int ct=0;ct<8;++ct) acc[ct] = (f32x4)0.0f;
  #pragma unroll
  for (int kt=0;kt<4;++kt){
    #pragma unroll
    for (int ct=0;ct<8;++ct){
      int row = ct*16+col4;
      const bf16x8 b = *(const bf16x8*)(Llds + row*128 + (((kt*4+grp)^(row&7))<<3));
      acc[ct] = __builtin_amdgcn_mfma_f32_16x16x32_bf16(xa[kt], b, acc[ct], 0,0,0);
    }
  }
  float ss[4] = {0,0,0,0}, dd[4] = {0,0,0,0};
  #pragma unroll
  for (int ct=0;ct<8;++ct)
    #pragma unroll
    for (int q=0;q<4;++q){
      float xv = acc[ct][q];
      int n = tile*16 + grp*4 + q;
      if (n < N) xbf[(size_t)n*128 + ct*16 + col4] = f2bf(xv);
      ss[q] += xv * ats[ct];
      dd[q] += xv * atd[ct];
    }
  #pragma unroll
  for (int m=1; m<16; m<<=1){
    #pragma unroll
    for (int q=0;q<4;++q){
      ss[q] += __shfl_xor(ss[q], m);
      dd[q] += __shfl_xor(dd[q], m);
    }
  }
  if (col4 == 0){
    #pragma unroll
    for (int q=0;q<4;++q){
      int n = tile*16 + grp*4 + q;
      if (n < N){ a_s[n] = ss[q]; a_d[n] = dd[q]; }
    }
  }
}

// ---------------- CSR aggregation: one wave per destination node, no atomics ----------------
__global__ __launch_bounds__(256) void k_agg2(
    const int* __restrict__ off, const int* __restrict__ eid,
    const float* __restrict__ a_s, const float* __restrict__ a_d,
    const unsigned short* __restrict__ xbf, const float* __restrict__ bias,
    float* __restrict__ out2, int N)
{
  int d = blockIdx.x*4 + (threadIdx.x >> 6);
  if (d >= N) return;
  const int lane = threadIdx.x & 63;
  const unsigned* xw = (const unsigned*)xbf;   // 2 bf16 channels per uint
  const float ad_d = a_d[d];
  // self loop
  float a0 = a_s[d] + ad_d; a0 = a0 > 0.f ? a0 : 0.2f*a0;
  float w = __expf(a0);
  unsigned pv = xw[(size_t)d*64 + lane];
  float den  = w;
  float acc0 = w * bf2f((unsigned short)(pv & 0xffffu));
  float acc1 = w * bf2f((unsigned short)(pv >> 16));
  const int i1 = off[d+1];
  for (int i = off[d]; i < i1; ++i){
    int s = eid[i];
    float a = a_s[s] + ad_d; a = a > 0.f ? a : 0.2f*a;
    float ww = __expf(a);
    unsigned pp = xw[(size_t)s*64 + lane];
    den  += ww;
    acc0 += ww * bf2f((unsigned short)(pp & 0xffffu));
    acc1 += ww * bf2f((unsigned short)(pp >> 16));
  }
  float inv = 1.0f/den;
  float2 o;
  o.x = acc0*inv + bias[2*lane];
  o.y = acc1*inv + bias[2*lane+1];
  *(float2*)(out2 + (size_t)d*128 + 2*lane) = o;
}

extern "C" void kernel_launch(void* const* d_in, const int* in_sizes, int n_in,
                              void* d_out, int out_size, void* d_ws, size_t ws_size,
                              hipStream_t stream)
{
  const float* seq  = (const float*)d_in[0];
  const void*  ei   = d_in[1];
  const float* Wihf = (const float*)d_in[2];
  const float* Whhf = (const float*)d_in[3];
  const float* bih  = (const float*)d_in[4];
  const float* bhh  = (const float*)d_in[5];
  const float* linw = (const float*)d_in[6];
  const float* atts = (const float*)d_in[7];
  const float* attd = (const float*)d_in[8];
  const float* gbias= (const float*)d_in[9];

  const int N  = in_sizes[0] / (16*128);
  const int E  = in_sizes[1] / 2;
  const int nT = (N + 15) / 16;

  char* ws = (char*)d_ws;
  size_t off_b = 0;
  auto alloc = [&](size_t bytes) -> char* {
    char* p = ws + off_b;
    off_b = (off_b + bytes + 255) & ~(size_t)255;
    return p;
  };
  unsigned short* Wih_sw = (unsigned short*)alloc(98304);
  unsigned short* Whh_sw = (unsigned short*)alloc(98304);
  unsigned short* lin_sw = (unsigned short*)alloc(32768);
  unsigned short* xbf    = (unsigned short*)alloc((size_t)N*128*2);
  float*    a_s    = (float*)   alloc((size_t)N*4);
  float*    a_d    = (float*)   alloc((size_t)N*4);
  float*    hstate = (float*)   alloc((size_t)nT*16*128*4);
  unsigned* flag   = (unsigned*)alloc(64);
  int*      srcA   = (int*)     alloc((size_t)E*4);
  int*      dstA   = (int*)     alloc((size_t)E*4);
  int*      deg    = (int*)     alloc((size_t)N*4);
  int*      offs   = (int*)     alloc((size_t)(N+1)*4);
  int*      cur    = (int*)     alloc((size_t)N*4);
  int*      eid    = (int*)     alloc((size_t)E*4);

  // choose largest timestep-chunk whose gi slab fits remaining workspace
  const size_t perT = (size_t)nT * 12288;   // bytes of gi per timestep
  int tch = 16;
  while (tch > 2 && off_b + (size_t)tch*perT > ws_size) tch >>= 1;
  unsigned short* gi = (unsigned short*)alloc((size_t)tch*perT);
  const int chunks = 16 / tch;

  float* hout = (float*)d_out;
  float* out2 = hout + (size_t)N*128;

  k_prep   <<<448, 256, 0, stream>>>(Wihf, Whhf, linw, Wih_sw, Whh_sw, lin_sw);
  k_detect <<<1, 64, 0, stream>>>((const int*)ei, flag);
  k_zero   <<<(N + 255)/256, 256, 0, stream>>>(deg, N);
  k_norm   <<<(E + 255)/256, 256, 0, stream>>>(ei, flag, srcA, dstA, deg, E);
  k_scan   <<<1, 64, 0, stream>>>(deg, offs, cur, N);
  k_scatter<<<(E + 255)/256, 256, 0, stream>>>(srcA, dstA, offs, cur, eid, E);

  for (int c = 0; c < chunks; ++c){
    k_phA<<<256, 512, 0, stream>>>(seq, Wih_sw, bih, bhh, gi, nT, N, tch, c);
    k_phB<<<256, 512, 0, stream>>>(Whh_sw, bhh, gi, hstate, hout, nT, N, tch, c, c == chunks-1);
  }

  k_gat1<<<(nT + 3)/4, 256, 0, stream>>>(hout, lin_sw, atts, attd, xbf, a_s, a_d, N, nT);
  k_agg2<<<(N + 3)/4, 256, 0, stream>>>(offs, eid, a_s, a_d, xbf, gbias, out2, N);
}